// Round 3
// baseline (245.405 us; speedup 1.0000x reference)
//
#include <hip/hip_runtime.h>
#include <hip/hip_bf16.h>
#include <cstdint>
#include <cstddef>

typedef __bf16 bf16_t;
typedef __bf16 bf16x8 __attribute__((ext_vector_type(8)));
typedef __bf16 bf16x4 __attribute__((ext_vector_type(4)));
typedef short short4v __attribute__((ext_vector_type(4)));
typedef float f32x4 __attribute__((ext_vector_type(4)));

#define NB 2
#define NT 2048
#define NC 1024
#define NH 16
#define ND 64
#define NM (NB * NT)   // 4096
#define N3 (3 * NC)    // 3072
// 1/sqrt(D) * log2(e): softmax done in exp2 domain
#define QSCALE_LOG2E 0.18033688011112042f

// async global->LDS, 16B per lane; LDS dest is wave-uniform base + lane*16
#define GLOAD_LDS16(gptr, lptr)                                                          \
  __builtin_amdgcn_global_load_lds((const __attribute__((address_space(1))) void*)(gptr), \
                                   (__attribute__((address_space(3))) void*)(lptr), 16, 0, 0)

// ---------------------------------------------------------------- casts
__global__ __launch_bounds__(256) void cast_f32_bf16_k(const float* __restrict__ in,
                                                       bf16_t* __restrict__ out, int n) {
  int i = (blockIdx.x * 256 + threadIdx.x) * 4;
  if (i + 3 < n) {
    const float4 v = *(const float4*)(in + i);
    bf16x4 o;
    o[0] = (bf16_t)v.x; o[1] = (bf16_t)v.y; o[2] = (bf16_t)v.z; o[3] = (bf16_t)v.w;
    *(bf16x4*)(out + i) = o;
  }
}

// out[c][r] = (bf16) in[r][c]   (in: R x Ccols fp32) -> B^T layout for GEMM
__global__ __launch_bounds__(256) void transpose_cast_k(const float* __restrict__ in,
                                                        bf16_t* __restrict__ out,
                                                        int R, int Ccols) {
  __shared__ float tile[32][33];
  int tc = blockIdx.x * 32;
  int tr = blockIdx.y * 32;
  int lx = threadIdx.x & 31;
  int ly = threadIdx.x >> 5;
#pragma unroll
  for (int i = 0; i < 32; i += 8)
    tile[ly + i][lx] = in[(size_t)(tr + ly + i) * Ccols + tc + lx];
  __syncthreads();
#pragma unroll
  for (int i = 0; i < 32; i += 8)
    out[(size_t)(tc + ly + i) * R + tr + lx] = (bf16_t)tile[lx][ly + i];
}

// ---------------------------------------------------------------- GEMM mainloop
// C[m,n] = sum_k A[m,k] * Bt[n,k]; A:[M,K] bf16, Bt:[N,K] bf16. 128x128 tile, 4 waves.
template <int K>
__device__ __forceinline__ void gemm_mainloop(const bf16_t* __restrict__ A,
                                              const bf16_t* __restrict__ Bt,
                                              int m0, int n0, f32x4 acc[4][4],
                                              bf16_t* lds) {
  bf16_t* As = lds;         // [128][32]
  bf16_t* Bs = lds + 4096;  // [128][32]
  const int tid = threadIdx.x;
  const int lane = tid & 63;
  const int w = tid >> 6;
  const int wm = (w & 1) * 64;
  const int wn = (w >> 1) * 64;
  const int quad = lane >> 4;
  const int l16 = lane & 15;

  for (int k0 = 0; k0 < K; k0 += 32) {
#pragma unroll
    for (int i = 0; i < 2; ++i) {
      const int gb = w * 128 + i * 64;   // group base (8 bf16 per group)
      const int g = gb + lane;
      GLOAD_LDS16(A + (size_t)(m0 + (g >> 2)) * K + k0 + (g & 3) * 8, As + gb * 8);
      GLOAD_LDS16(Bt + (size_t)(n0 + (g >> 2)) * K + k0 + (g & 3) * 8, Bs + gb * 8);
    }
    __syncthreads();
    bf16x8 af[4], bfr[4];
#pragma unroll
    for (int i = 0; i < 4; ++i)
      af[i] = *(const bf16x8*)(As + (wm + i * 16 + l16) * 32 + quad * 8);
#pragma unroll
    for (int j = 0; j < 4; ++j)
      bfr[j] = *(const bf16x8*)(Bs + (wn + j * 16 + l16) * 32 + quad * 8);
#pragma unroll
    for (int i = 0; i < 4; ++i)
#pragma unroll
      for (int j = 0; j < 4; ++j)
        acc[i][j] = __builtin_amdgcn_mfma_f32_16x16x32_bf16(af[i], bfr[j], acc[i][j], 0, 0, 0);
    __syncthreads();
  }
}

// ---------------------------------------------------------------- QKV GEMM
// A = x bf16 [4096,1024]; Bt = Wqkv^T [3072,1024].
// q PRE-SCALED by log2(e)/sqrt(D) (softmax in exp2 domain).
// Epilogue: q,k,v all stored [B,H,T,D] (fully coalesced; v repacked later).
__global__ __launch_bounds__(256) void qkv_gemm_k(const bf16_t* __restrict__ A,
                                                  const bf16_t* __restrict__ Bt,
                                                  const float* __restrict__ bias,
                                                  bf16_t* __restrict__ qb,
                                                  bf16_t* __restrict__ kb,
                                                  bf16_t* __restrict__ vb) {
  __shared__ __align__(16) bf16_t lds[8192];
  const int m0 = blockIdx.y * 128, n0 = blockIdx.x * 128;
  f32x4 acc[4][4] = {};
  gemm_mainloop<NC>(A, Bt, m0, n0, acc, lds);

  const int lane = threadIdx.x & 63;
  const int w = threadIdx.x >> 6;
  const int wm = (w & 1) * 64, wn = (w >> 1) * 64;
  const int quad = lane >> 4, l16 = lane & 15;
#pragma unroll
  for (int i = 0; i < 4; ++i)
#pragma unroll
    for (int j = 0; j < 4; ++j) {
      const int n = n0 + wn + j * 16 + l16;
      const float bn = bias[n];
      const int which = n >> 10;        // 0=q 1=k 2=v
      const int rem = n & 1023;
      const int h = rem >> 6, d = rem & 63;
      bf16_t* dst = (which == 0) ? qb : (which == 1) ? kb : vb;
      const float sc = (which == 0) ? QSCALE_LOG2E : 1.0f;
#pragma unroll
      for (int r = 0; r < 4; ++r) {
        const int m = m0 + wm + i * 16 + quad * 4 + r;  // C/D: row=(lane>>4)*4+reg
        const int b = m >> 11, t = m & 2047;
        const size_t bh = (size_t)b * NH + h;
        dst[(bh * NT + t) * ND + d] = (bf16_t)((acc[i][j][r] + bn) * sc);
      }
    }
}

// ---------------------------------------------------------------- V repack
// v[bh][t][d] -> vt2[bh][c][g][d][j], t = c*64 + g*4 + j  (frag-ready for x16_1k A)
__global__ __launch_bounds__(256) void vtile_k(const bf16_t* __restrict__ v,
                                               bf16_t* __restrict__ vt2) {
  const int bh = blockIdx.x >> 5, c = blockIdx.x & 31;
  const bf16_t* src = v + ((size_t)bh * NT + c * 64) * ND;
  bf16_t* dst = vt2 + ((size_t)bh * 32 + c) * 4096;
#pragma unroll
  for (int it = 0; it < 4; ++it) {
    const int slot = it * 256 + threadIdx.x;  // g*64 + d
    const int g = slot >> 6, d = slot & 63;
    bf16x4 val;
#pragma unroll
    for (int j = 0; j < 4; ++j) val[j] = src[(size_t)(g * 4 + j) * ND + d];
    *(bf16x4*)(dst + (size_t)slot * 4) = val;
  }
}

// ---------------------------------------------------------------- attention v3
// LDS-free, barrier-free. Wave = 16 queries (lane l16 owns one query).
// S^T = K*Q^T via x32 MFMA (A=K frags straight from global, coalesced dwordx4).
// P^T stays in registers (C-layout == x16_1k B-layout). O^T += V^T*P^T with
// V^T A-frags loaded from frag-ready vt2 (coalesced dwordx2). No __syncthreads.
__global__ __launch_bounds__(256, 4) void attn_k(const bf16_t* __restrict__ q,
                                                 const bf16_t* __restrict__ k,
                                                 const bf16_t* __restrict__ vt2,
                                                 bf16_t* __restrict__ y /*[B,T,C]*/) {
  const int bh = blockIdx.x & 31;   // same-bh blocks land on same XCD (stride-32 grid)
  const int s = blockIdx.x >> 5;    // 0..31
  const int w = threadIdx.x >> 6;
  // per-block constant work: tiles {s, 63-s, 64+s, 127-s} -> 66 chunk-steps total
  const int tile = (w >> 1) * 64 + ((w & 1) ? (63 - s) : s);
  const int lane = threadIdx.x & 63;
  const int quad = lane >> 4, l16 = lane & 15;
  const int qv = tile * 16 + l16;   // this lane's query
  const int b = bh >> 4, h = bh & 15;

  const bf16_t* qp = q + (size_t)bh * NT * ND;
  const bf16_t* kp = k + (size_t)bh * NT * ND;
  const bf16_t* vp = vt2 + (size_t)bh * 32 * 4096;

  // Q fragments (x32 B-operand: lane l16 = query col, k = quad*8+i)
  const bf16x8 qf0 = *(const bf16x8*)(qp + (size_t)qv * ND + quad * 8);
  const bf16x8 qf1 = *(const bf16x8*)(qp + (size_t)qv * ND + 32 + quad * 8);

  float m = -INFINITY, l = 0.f;
  f32x4 o[4];
#pragma unroll
  for (int dj = 0; dj < 4; ++dj) o[dj] = (f32x4){0.f, 0.f, 0.f, 0.f};

  const int c0 = tile >> 2;  // first key-chunk
  for (int c = c0; c < 32; ++c) {
    const int t0 = c * 64;
    const bf16_t* kc = kp + (size_t)t0 * ND;
    const bf16_t* vc = vp + (size_t)c * 4096;

    // ---- S^T = K . Q^T  (keys kj*16+quad*4+r , query l16)
    f32x4 sv[4];
#pragma unroll
    for (int kj = 0; kj < 4; ++kj) {
      const bf16_t* krow = kc + (size_t)(kj * 16 + l16) * ND;
      const bf16x8 a0 = *(const bf16x8*)(krow + quad * 8);
      const bf16x8 a1 = *(const bf16x8*)(krow + 32 + quad * 8);
      f32x4 z = {0.f, 0.f, 0.f, 0.f};
      z = __builtin_amdgcn_mfma_f32_16x16x32_bf16(a0, qf0, z, 0, 0, 0);
      z = __builtin_amdgcn_mfma_f32_16x16x32_bf16(a1, qf1, z, 0, 0, 0);
      sv[kj] = z;
    }
    if (c == c0) {  // diagonal chunk: keep k >= q
#pragma unroll
      for (int kj = 0; kj < 4; ++kj)
#pragma unroll
        for (int r = 0; r < 4; ++r)
          if (t0 + kj * 16 + quad * 4 + r < qv) sv[kj][r] = -INFINITY;
    }
    // ---- online softmax (exp2 domain; scale folded into q)
    float mx = -INFINITY;
#pragma unroll
    for (int kj = 0; kj < 4; ++kj)
#pragma unroll
      for (int r = 0; r < 4; ++r) mx = fmaxf(mx, sv[kj][r]);
    mx = fmaxf(mx, __shfl_xor(mx, 16));
    mx = fmaxf(mx, __shfl_xor(mx, 32));
    const float mnew = fmaxf(m, mx);
    const float alpha = exp2f(m - mnew);
    m = mnew;
    float rs = 0.f;
#pragma unroll
    for (int kj = 0; kj < 4; ++kj)
#pragma unroll
      for (int r = 0; r < 4; ++r) {
        const float p = exp2f(sv[kj][r] - mnew);
        sv[kj][r] = p;
        rs += p;
      }
    rs += __shfl_xor(rs, 16);
    rs += __shfl_xor(rs, 32);
    l = l * alpha + rs;
    // pack P^T frags (x16_1k B-operand: n=l16 query, k=quad*4+r) — in-lane already
    short4v pf[4];
#pragma unroll
    for (int kj = 0; kj < 4; ++kj) {
      bf16x4 pb;
#pragma unroll
      for (int r = 0; r < 4; ++r) pb[r] = (bf16_t)sv[kj][r];
      pf[kj] = __builtin_bit_cast(short4v, pb);
    }
    // ---- O^T += V^T . P^T   (A-frags from frag-ready vt2, coalesced 8B loads)
#pragma unroll
    for (int dj = 0; dj < 4; ++dj) {
      o[dj][0] *= alpha; o[dj][1] *= alpha; o[dj][2] *= alpha; o[dj][3] *= alpha;
#pragma unroll
      for (int kj = 0; kj < 4; ++kj) {
        const bf16x4 a =
            *(const bf16x4*)(vc + ((size_t)(kj * 4 + quad) * 64 + dj * 16 + l16) * 4);
        o[dj] = __builtin_amdgcn_mfma_f32_16x16x16bf16_1k(
            __builtin_bit_cast(short4v, a), pf[kj], o[dj], 0, 0, 0);
      }
    }
  }

  // store O^T -> y [B,T,C]: d = dj*16 + quad*4 + r (contiguous per reg)
  const float inv = 1.0f / l;
  const size_t base = ((size_t)b * NT + qv) * NC + h * 64;
#pragma unroll
  for (int dj = 0; dj < 4; ++dj) {
    bf16x4 va;
#pragma unroll
    for (int r = 0; r < 4; ++r) va[r] = (bf16_t)(o[dj][r] * inv);
    *(bf16x4*)(y + base + dj * 16 + quad * 4) = va;
  }
}

// ---------------------------------------------------------------- out projection
__global__ __launch_bounds__(256) void out_gemm_k(const bf16_t* __restrict__ A,
                                                  const bf16_t* __restrict__ Bt,
                                                  const float* __restrict__ bias,
                                                  float* __restrict__ out) {
  __shared__ __align__(16) bf16_t lds[8192];
  const int m0 = blockIdx.y * 128, n0 = blockIdx.x * 128;
  f32x4 acc[4][4] = {};
  gemm_mainloop<NC>(A, Bt, m0, n0, acc, lds);

  const int lane = threadIdx.x & 63;
  const int w = threadIdx.x >> 6;
  const int wm = (w & 1) * 64, wn = (w >> 1) * 64;
  const int quad = lane >> 4, l16 = lane & 15;
#pragma unroll
  for (int i = 0; i < 4; ++i)
#pragma unroll
    for (int j = 0; j < 4; ++j) {
      const int n = n0 + wn + j * 16 + l16;
      const float bn = bias[n];
#pragma unroll
      for (int r = 0; r < 4; ++r) {
        const int m = m0 + wm + i * 16 + quad * 4 + r;
        out[(size_t)m * NC + n] = acc[i][j][r] + bn;
      }
    }
}

// ---------------------------------------------------------------- launch
extern "C" void kernel_launch(void* const* d_in, const int* in_sizes, int n_in,
                              void* d_out, int out_size, void* d_ws, size_t ws_size,
                              hipStream_t stream) {
  const float* x = (const float*)d_in[0];
  const float* Wqkv = (const float*)d_in[1];
  const float* bqkv = (const float*)d_in[2];
  const float* Wo = (const float*)d_in[3];
  const float* bo = (const float*)d_in[4];
  float* out = (float*)d_out;

  char* p = (char*)d_ws;
  bf16_t* xbf = (bf16_t*)p;   p += (size_t)NM * NC * sizeof(bf16_t);        // 8 MB
  bf16_t* wqkvT = (bf16_t*)p; p += (size_t)N3 * NC * sizeof(bf16_t);        // 6 MB
  bf16_t* woT = (bf16_t*)p;   p += (size_t)NC * NC * sizeof(bf16_t);        // 2 MB
  bf16_t* qb = (bf16_t*)p;    p += (size_t)NB * NH * NT * ND * sizeof(bf16_t); // 8 MB
  bf16_t* kb = (bf16_t*)p;    p += (size_t)NB * NH * NT * ND * sizeof(bf16_t); // 8 MB
  bf16_t* vb = (bf16_t*)p;    p += (size_t)NB * NH * NT * ND * sizeof(bf16_t); // 8 MB
  bf16_t* yb = (bf16_t*)p;    p += (size_t)NM * NC * sizeof(bf16_t);        // 8 MB
  bf16_t* vt2 = xbf;  // reuse: xbf is dead after qkv_gemm_k (same-stream ordering)

  hipLaunchKernelGGL(cast_f32_bf16_k, dim3(NM * NC / 1024), dim3(256), 0, stream,
                     x, xbf, NM * NC);
  hipLaunchKernelGGL(transpose_cast_k, dim3(N3 / 32, NC / 32), dim3(256), 0, stream,
                     Wqkv, wqkvT, NC, N3);
  hipLaunchKernelGGL(transpose_cast_k, dim3(NC / 32, NC / 32), dim3(256), 0, stream,
                     Wo, woT, NC, NC);
  hipLaunchKernelGGL(qkv_gemm_k, dim3(N3 / 128, NM / 128), dim3(256), 0, stream,
                     xbf, wqkvT, bqkv, qb, kb, vb);
  hipLaunchKernelGGL(vtile_k, dim3(32 * 32), dim3(256), 0, stream, vb, vt2);
  hipLaunchKernelGGL(attn_k, dim3(1024), dim3(256), 0, stream, qb, kb, vt2, yb);
  hipLaunchKernelGGL(out_gemm_k, dim3(NC / 128, NM / 128), dim3(256), 0, stream,
                     yb, woT, bo, out);
}

// Round 4
// 194.552 us; speedup vs baseline: 1.2614x; 1.2614x over previous
//
#include <hip/hip_runtime.h>
#include <hip/hip_bf16.h>
#include <cstdint>
#include <cstddef>

typedef __bf16 bf16_t;
typedef __bf16 bf16x8 __attribute__((ext_vector_type(8)));
typedef __bf16 bf16x4 __attribute__((ext_vector_type(4)));
typedef short short4v __attribute__((ext_vector_type(4)));
typedef float f32x4 __attribute__((ext_vector_type(4)));

#define NB 2
#define NT 2048
#define NC 1024
#define NH 16
#define ND 64
#define NM (NB * NT)   // 4096
#define N3 (3 * NC)    // 3072
// 1/sqrt(D) * log2(e): softmax done in exp2 domain
#define QSCALE_LOG2E 0.18033688011112042f

// async global->LDS, 16B per lane; LDS dest is wave-uniform base + lane*16
#define GLOAD_LDS16(gptr, lptr)                                                          \
  __builtin_amdgcn_global_load_lds((const __attribute__((address_space(1))) void*)(gptr), \
                                   (__attribute__((address_space(3))) void*)(lptr), 16, 0, 0)

// ---------------------------------------------------------------- casts
__global__ __launch_bounds__(256) void cast_f32_bf16_k(const float* __restrict__ in,
                                                       bf16_t* __restrict__ out, int n) {
  int i = (blockIdx.x * 256 + threadIdx.x) * 4;
  if (i + 3 < n) {
    const float4 v = *(const float4*)(in + i);
    bf16x4 o;
    o[0] = (bf16_t)v.x; o[1] = (bf16_t)v.y; o[2] = (bf16_t)v.z; o[3] = (bf16_t)v.w;
    *(bf16x4*)(out + i) = o;
  }
}

// out[c][r] = (bf16) in[r][c]   (in: R x Ccols fp32) -> B^T layout for GEMM
__global__ __launch_bounds__(256) void transpose_cast_k(const float* __restrict__ in,
                                                        bf16_t* __restrict__ out,
                                                        int R, int Ccols) {
  __shared__ float tile[32][33];
  int tc = blockIdx.x * 32;
  int tr = blockIdx.y * 32;
  int lx = threadIdx.x & 31;
  int ly = threadIdx.x >> 5;
#pragma unroll
  for (int i = 0; i < 32; i += 8)
    tile[ly + i][lx] = in[(size_t)(tr + ly + i) * Ccols + tc + lx];
  __syncthreads();
#pragma unroll
  for (int i = 0; i < 32; i += 8)
    out[(size_t)(tc + ly + i) * R + tr + lx] = (bf16_t)tile[lx][ly + i];
}

// ---------------------------------------------------------------- GEMM mainloop
// C[m,n] = sum_k A[m,k] * Bt[n,k]; A:[M,K] bf16, Bt:[N,K] bf16. 128x128 tile, 4 waves.
template <int K>
__device__ __forceinline__ void gemm_mainloop(const bf16_t* __restrict__ A,
                                              const bf16_t* __restrict__ Bt,
                                              int m0, int n0, f32x4 acc[4][4],
                                              bf16_t* lds) {
  bf16_t* As = lds;         // [128][32]
  bf16_t* Bs = lds + 4096;  // [128][32]
  const int tid = threadIdx.x;
  const int lane = tid & 63;
  const int w = tid >> 6;
  const int wm = (w & 1) * 64;
  const int wn = (w >> 1) * 64;
  const int quad = lane >> 4;
  const int l16 = lane & 15;

  for (int k0 = 0; k0 < K; k0 += 32) {
#pragma unroll
    for (int i = 0; i < 2; ++i) {
      const int gb = w * 128 + i * 64;   // group base (8 bf16 per group)
      const int g = gb + lane;
      GLOAD_LDS16(A + (size_t)(m0 + (g >> 2)) * K + k0 + (g & 3) * 8, As + gb * 8);
      GLOAD_LDS16(Bt + (size_t)(n0 + (g >> 2)) * K + k0 + (g & 3) * 8, Bs + gb * 8);
    }
    __syncthreads();
    bf16x8 af[4], bfr[4];
#pragma unroll
    for (int i = 0; i < 4; ++i)
      af[i] = *(const bf16x8*)(As + (wm + i * 16 + l16) * 32 + quad * 8);
#pragma unroll
    for (int j = 0; j < 4; ++j)
      bfr[j] = *(const bf16x8*)(Bs + (wn + j * 16 + l16) * 32 + quad * 8);
#pragma unroll
    for (int i = 0; i < 4; ++i)
#pragma unroll
      for (int j = 0; j < 4; ++j)
        acc[i][j] = __builtin_amdgcn_mfma_f32_16x16x32_bf16(af[i], bfr[j], acc[i][j], 0, 0, 0);
    __syncthreads();
  }
}

// ---------------------------------------------------------------- QKV GEMM
// A = x bf16 [4096,1024]; Bt = Wqkv^T [3072,1024].
// q PRE-SCALED by log2(e)/sqrt(D) (softmax in exp2 domain).
// Epilogue: q,k,v all stored [B,H,T,D] (fully coalesced; v repacked later).
__global__ __launch_bounds__(256) void qkv_gemm_k(const bf16_t* __restrict__ A,
                                                  const bf16_t* __restrict__ Bt,
                                                  const float* __restrict__ bias,
                                                  bf16_t* __restrict__ qb,
                                                  bf16_t* __restrict__ kb,
                                                  bf16_t* __restrict__ vb) {
  __shared__ __align__(16) bf16_t lds[8192];
  const int m0 = blockIdx.y * 128, n0 = blockIdx.x * 128;
  f32x4 acc[4][4] = {};
  gemm_mainloop<NC>(A, Bt, m0, n0, acc, lds);

  const int lane = threadIdx.x & 63;
  const int w = threadIdx.x >> 6;
  const int wm = (w & 1) * 64, wn = (w >> 1) * 64;
  const int quad = lane >> 4, l16 = lane & 15;
#pragma unroll
  for (int i = 0; i < 4; ++i)
#pragma unroll
    for (int j = 0; j < 4; ++j) {
      const int n = n0 + wn + j * 16 + l16;
      const float bn = bias[n];
      const int which = n >> 10;        // 0=q 1=k 2=v
      const int rem = n & 1023;
      const int h = rem >> 6, d = rem & 63;
      bf16_t* dst = (which == 0) ? qb : (which == 1) ? kb : vb;
      const float sc = (which == 0) ? QSCALE_LOG2E : 1.0f;
#pragma unroll
      for (int r = 0; r < 4; ++r) {
        const int m = m0 + wm + i * 16 + quad * 4 + r;  // C/D: row=(lane>>4)*4+reg
        const int b = m >> 11, t = m & 2047;
        const size_t bh = (size_t)b * NH + h;
        dst[(bh * NT + t) * ND + d] = (bf16_t)((acc[i][j][r] + bn) * sc);
      }
    }
}

// ---------------------------------------------------------------- V repack
// v[bh][t][d] -> vt2[bh][c][g][d][j], t = c*64 + g*4 + j  (frag-ready for x16_1k A)
__global__ __launch_bounds__(256) void vtile_k(const bf16_t* __restrict__ v,
                                               bf16_t* __restrict__ vt2) {
  const int bh = blockIdx.x >> 5, c = blockIdx.x & 31;
  const bf16_t* src = v + ((size_t)bh * NT + c * 64) * ND;
  bf16_t* dst = vt2 + ((size_t)bh * 32 + c) * 4096;
#pragma unroll
  for (int it = 0; it < 4; ++it) {
    const int slot = it * 256 + threadIdx.x;  // g*64 + d
    const int g = slot >> 6, d = slot & 63;
    bf16x4 val;
#pragma unroll
    for (int j = 0; j < 4; ++j) val[j] = src[(size_t)(g * 4 + j) * ND + d];
    *(bf16x4*)(dst + (size_t)slot * 4) = val;
  }
}

// ---------------------------------------------------------------- attention v4
// Block = one (b,h) x one 64-query tile (wave w owns queries T*64+w*16+l16).
// Grid 1024 = 4 blocks/CU; round-swizzled tile map gives each CU exactly 66 steps.
// Double-buffered LDS staging: K (XOR-swizzled rows) + V (frag-ready from vt2);
// chunk c+1 is issued before computing chunk c, so the barrier's vmcnt drain
// lands a full compute-phase after issue.
__global__ __launch_bounds__(256, 4) void attn_k(const bf16_t* __restrict__ q,
                                                 const bf16_t* __restrict__ k,
                                                 const bf16_t* __restrict__ vt2,
                                                 bf16_t* __restrict__ y /*[B,T,C]*/) {
  const int bh = blockIdx.x & 31;
  const int u = (blockIdx.x >> 5) & 7;
  const int r4 = blockIdx.x >> 8;                    // dispatch round 0..3
  const int T = r4 * 8 + ((r4 & 1) ? (7 - u) : u);   // CU-constant total work
  const int b = bh >> 4, h = bh & 15;

  const bf16_t* qp = q + (size_t)bh * NT * ND;
  const bf16_t* kp = k + (size_t)bh * NT * ND;
  const bf16_t* vp = vt2 + (size_t)bh * 32 * 4096;

  __shared__ __align__(16) bf16_t kbuf[2][4096];
  __shared__ __align__(16) bf16_t vbuf[2][4096];

  const int lane = threadIdx.x & 63;
  const int w = threadIdx.x >> 6;
  const int quad = lane >> 4, l16 = lane & 15;
  const int qv = T * 64 + w * 16 + l16;  // this lane's query

  // Q fragments (x32 B-operand: lane l16 = query col, k = quad*8+i)
  const bf16x8 qf0 = *(const bf16x8*)(qp + (size_t)qv * ND + quad * 8);
  const bf16x8 qf1 = *(const bf16x8*)(qp + (size_t)qv * ND + 32 + quad * 8);

  float m = -INFINITY, l = 0.f;
  f32x4 o[4];
#pragma unroll
  for (int dj = 0; dj < 4; ++dj) o[dj] = (f32x4){0.f, 0.f, 0.f, 0.f};

  // ---- staging helper: chunk c into buffer bi
  auto stage = [&](int c, int bi) {
    const bf16_t* kc = kp + (size_t)c * 64 * ND;   // 8KB contiguous (64 rows x 128B)
    const bf16_t* vc = vp + (size_t)c * 4096;      // 8KB contiguous frag-ready
#pragma unroll
    for (int i = 0; i < 2; ++i) {
      const int gb = w * 128 + i * 64;             // granule base for this GLOAD
      const int s = gb + lane;                     // LDS granule this lane fills
      const int row = s >> 3;
      const int cs = (s & 7) ^ (row & 7);          // XOR swizzle for K rows
      GLOAD_LDS16(kc + ((size_t)row * 8 + cs) * 8, kbuf[bi] + gb * 8);
      GLOAD_LDS16(vc + (size_t)s * 8, vbuf[bi] + gb * 8);
    }
  };

  stage(T, 0);
  int cur = 0;
  for (int c = T; c < 32; ++c) {
    __syncthreads();  // stage(c) visible to all waves (issued one compute-phase ago)
    if (c + 1 < 32) stage(c + 1, cur ^ 1);

    const bf16_t* kt = kbuf[cur];
    const bf16_t* vt = vbuf[cur];
    const int t0 = c * 64;

    // ---- S^T = K . Q^T  (keys kj*16+quad*4+r , query l16)
    f32x4 sv[4];
#pragma unroll
    for (int kj = 0; kj < 4; ++kj) {
      const int kr = kj * 16 + l16;
      const int sw = kr & 7;
      const bf16x8 a0 = *(const bf16x8*)(kt + ((size_t)kr * 8 + (quad ^ sw)) * 8);
      const bf16x8 a1 = *(const bf16x8*)(kt + ((size_t)kr * 8 + ((4 + quad) ^ sw)) * 8);
      f32x4 z = {0.f, 0.f, 0.f, 0.f};
      z = __builtin_amdgcn_mfma_f32_16x16x32_bf16(a0, qf0, z, 0, 0, 0);
      z = __builtin_amdgcn_mfma_f32_16x16x32_bf16(a1, qf1, z, 0, 0, 0);
      sv[kj] = z;
    }
    if (c == T) {  // diagonal chunk: keep k >= q
#pragma unroll
      for (int kj = 0; kj < 4; ++kj)
#pragma unroll
        for (int r = 0; r < 4; ++r)
          if (t0 + kj * 16 + quad * 4 + r < qv) sv[kj][r] = -INFINITY;
    }
    // ---- online softmax (exp2 domain; scale folded into q)
    float mx = -INFINITY;
#pragma unroll
    for (int kj = 0; kj < 4; ++kj)
#pragma unroll
      for (int r = 0; r < 4; ++r) mx = fmaxf(mx, sv[kj][r]);
    mx = fmaxf(mx, __shfl_xor(mx, 16));
    mx = fmaxf(mx, __shfl_xor(mx, 32));
    const float mnew = fmaxf(m, mx);
    const float alpha = exp2f(m - mnew);
    m = mnew;
    float rs = 0.f;
#pragma unroll
    for (int kj = 0; kj < 4; ++kj)
#pragma unroll
      for (int r = 0; r < 4; ++r) {
        const float p = exp2f(sv[kj][r] - mnew);
        sv[kj][r] = p;
        rs += p;
      }
    rs += __shfl_xor(rs, 16);
    rs += __shfl_xor(rs, 32);
    l = l * alpha + rs;
    // pack P^T frags (x16_1k B-operand: n=l16 query, k=quad*4+r) — in-lane already
    short4v pf[4];
#pragma unroll
    for (int kj = 0; kj < 4; ++kj) {
      bf16x4 pb;
#pragma unroll
      for (int r = 0; r < 4; ++r) pb[r] = (bf16_t)sv[kj][r];
      pf[kj] = __builtin_bit_cast(short4v, pb);
    }
    // ---- O^T += V^T . P^T   (A-frags from frag-ready vbuf)
#pragma unroll
    for (int dj = 0; dj < 4; ++dj) {
      o[dj][0] *= alpha; o[dj][1] *= alpha; o[dj][2] *= alpha; o[dj][3] *= alpha;
#pragma unroll
      for (int kj = 0; kj < 4; ++kj) {
        const bf16x4 a =
            *(const bf16x4*)(vt + ((size_t)(kj * 4 + quad) * 64 + dj * 16 + l16) * 4);
        o[dj] = __builtin_amdgcn_mfma_f32_16x16x16bf16_1k(
            __builtin_bit_cast(short4v, a), pf[kj], o[dj], 0, 0, 0);
      }
    }
    cur ^= 1;
  }

  // store O^T -> y [B,T,C]: d = dj*16 + quad*4 + r (contiguous per reg)
  const float inv = 1.0f / l;
  const size_t base = ((size_t)b * NT + qv) * NC + h * 64;
#pragma unroll
  for (int dj = 0; dj < 4; ++dj) {
    bf16x4 va;
#pragma unroll
    for (int r = 0; r < 4; ++r) va[r] = (bf16_t)(o[dj][r] * inv);
    *(bf16x4*)(y + base + dj * 16 + quad * 4) = va;
  }
}

// ---------------------------------------------------------------- out projection
__global__ __launch_bounds__(256) void out_gemm_k(const bf16_t* __restrict__ A,
                                                  const bf16_t* __restrict__ Bt,
                                                  const float* __restrict__ bias,
                                                  float* __restrict__ out) {
  __shared__ __align__(16) bf16_t lds[8192];
  const int m0 = blockIdx.y * 128, n0 = blockIdx.x * 128;
  f32x4 acc[4][4] = {};
  gemm_mainloop<NC>(A, Bt, m0, n0, acc, lds);

  const int lane = threadIdx.x & 63;
  const int w = threadIdx.x >> 6;
  const int wm = (w & 1) * 64, wn = (w >> 1) * 64;
  const int quad = lane >> 4, l16 = lane & 15;
#pragma unroll
  for (int i = 0; i < 4; ++i)
#pragma unroll
    for (int j = 0; j < 4; ++j) {
      const int n = n0 + wn + j * 16 + l16;
      const float bn = bias[n];
#pragma unroll
      for (int r = 0; r < 4; ++r) {
        const int m = m0 + wm + i * 16 + quad * 4 + r;
        out[(size_t)m * NC + n] = acc[i][j][r] + bn;
      }
    }
}

// ---------------------------------------------------------------- launch
extern "C" void kernel_launch(void* const* d_in, const int* in_sizes, int n_in,
                              void* d_out, int out_size, void* d_ws, size_t ws_size,
                              hipStream_t stream) {
  const float* x = (const float*)d_in[0];
  const float* Wqkv = (const float*)d_in[1];
  const float* bqkv = (const float*)d_in[2];
  const float* Wo = (const float*)d_in[3];
  const float* bo = (const float*)d_in[4];
  float* out = (float*)d_out;

  char* p = (char*)d_ws;
  bf16_t* xbf = (bf16_t*)p;   p += (size_t)NM * NC * sizeof(bf16_t);        // 8 MB
  bf16_t* wqkvT = (bf16_t*)p; p += (size_t)N3 * NC * sizeof(bf16_t);        // 6 MB
  bf16_t* woT = (bf16_t*)p;   p += (size_t)NC * NC * sizeof(bf16_t);        // 2 MB
  bf16_t* qb = (bf16_t*)p;    p += (size_t)NB * NH * NT * ND * sizeof(bf16_t); // 8 MB
  bf16_t* kb = (bf16_t*)p;    p += (size_t)NB * NH * NT * ND * sizeof(bf16_t); // 8 MB
  bf16_t* vb = (bf16_t*)p;    p += (size_t)NB * NH * NT * ND * sizeof(bf16_t); // 8 MB
  bf16_t* yb = (bf16_t*)p;    p += (size_t)NM * NC * sizeof(bf16_t);        // 8 MB
  bf16_t* vt2 = xbf;  // reuse: xbf is dead after qkv_gemm_k (same-stream ordering)

  hipLaunchKernelGGL(cast_f32_bf16_k, dim3(NM * NC / 1024), dim3(256), 0, stream,
                     x, xbf, NM * NC);
  hipLaunchKernelGGL(transpose_cast_k, dim3(N3 / 32, NC / 32), dim3(256), 0, stream,
                     Wqkv, wqkvT, NC, N3);
  hipLaunchKernelGGL(transpose_cast_k, dim3(NC / 32, NC / 32), dim3(256), 0, stream,
                     Wo, woT, NC, NC);
  hipLaunchKernelGGL(qkv_gemm_k, dim3(N3 / 128, NM / 128), dim3(256), 0, stream,
                     xbf, wqkvT, bqkv, qb, kb, vb);
  hipLaunchKernelGGL(vtile_k, dim3(32 * 32), dim3(256), 0, stream, vb, vt2);
  hipLaunchKernelGGL(attn_k, dim3(1024), dim3(256), 0, stream, qb, kb, vt2, yb);
  hipLaunchKernelGGL(out_gemm_k, dim3(NC / 128, NM / 128), dim3(256), 0, stream,
                     yb, woT, bo, out);
}